// Round 2
// baseline (45.617 us; speedup 1.0000x reference)
//
#include <hip/hip_runtime.h>

typedef __attribute__((ext_vector_type(8))) short bf16x8;   // 8 bf16 (4 VGPRs)
typedef __attribute__((ext_vector_type(4))) float f32x4;

#define BM 128
#define BN 128
#define BK 64
#define LDP 72   // padded LDS leading dim (bf16): 144 B = 9*16 -> 16B-aligned rows, conflict-free

__device__ inline unsigned short f2bf(float f) {
  unsigned int u = __builtin_bit_cast(unsigned int, f);
  u += 0x7fffu + ((u >> 16) & 1u);     // round-to-nearest-even
  return (unsigned short)(u >> 16);
}

// Single fused kernel: out[m][n] = ||F_m||^2 + ||C_n||^2 - 2*F_m.C_n
// F: M x 256 fp32, C: N x 256 fp32, out: M x N fp32.
// 128x128 tile, BK=64, 4 waves (2x2), 16x16x32 bf16 MFMA.
// A and B are reg-staged (fp32 load -> bf16 cvt -> padded LDS); row norms
// accumulated exactly in fp32 during conversion.
__global__ __launch_bounds__(256) void dist_fused(
    const float* __restrict__ F, const float* __restrict__ C,
    float* __restrict__ out, int M, int N) {
  __shared__ unsigned short As[BM * LDP];
  __shared__ unsigned short Bs[BN * LDP];
  __shared__ float fsq_s[BM];
  __shared__ float csq_s[BN];

  const int t = threadIdx.x;
  const int w = t >> 6, lane = t & 63;
  const int wr = w >> 1, wc = w & 1;          // wave -> 64x64 quadrant
  const int rl = lane & 15, kh = lane >> 4;   // fragment lane decomposition

  // Bijective XCD swizzle: nwg % 8 == 0 (1024 blocks). Each XCD gets a
  // contiguous chunk; n-tile fastest so the 4 blocks sharing an A m-panel
  // run consecutively on the SAME XCD -> A panel L2-hot, HBM-read once.
  const int nwg = gridDim.x;
  const int cpx = nwg >> 3;
  const int work = (blockIdx.x & 7) * cpx + (blockIdx.x >> 3);
  const int ntiles = N / BN;                  // 4
  const int n0 = (work % ntiles) * BN;
  const int m0 = (work / ntiles) * BM;

  const int srow = t >> 4;          // 0..15: row within 16-row chunk
  const int scol = (t & 15) * 4;    // 0..60: fp32 col offset within K-tile

  f32x4 acc[4][4];
#pragma unroll
  for (int i = 0; i < 4; i++)
#pragma unroll
    for (int j = 0; j < 4; j++) acc[i][j] = (f32x4){0.f, 0.f, 0.f, 0.f};

  float rsqA[8], rsqB[8];
#pragma unroll
  for (int i = 0; i < 8; i++) { rsqA[i] = 0.f; rsqB[i] = 0.f; }

  float4 rA[8], rB[8];
  // prologue: issue loads for kt=0
#pragma unroll
  for (int i = 0; i < 8; i++) {
    rA[i] = *reinterpret_cast<const float4*>(&F[(size_t)(m0 + i * 16 + srow) * 256 + scol]);
    rB[i] = *reinterpret_cast<const float4*>(&C[(size_t)(n0 + i * 16 + srow) * 256 + scol]);
  }

  for (int kt = 0; kt < 256; kt += BK) {
    // convert current tile -> LDS, accumulate exact fp32 squares
#pragma unroll
    for (int i = 0; i < 8; i++) {
      const float4 a = rA[i];
      rsqA[i] += a.x * a.x + a.y * a.y + a.z * a.z + a.w * a.w;
      ushort4 ab;
      ab.x = f2bf(a.x); ab.y = f2bf(a.y); ab.z = f2bf(a.z); ab.w = f2bf(a.w);
      *reinterpret_cast<ushort4*>(&As[(i * 16 + srow) * LDP + (t & 15) * 4]) = ab;
      const float4 b = rB[i];
      rsqB[i] += b.x * b.x + b.y * b.y + b.z * b.z + b.w * b.w;
      ushort4 bb;
      bb.x = f2bf(b.x); bb.y = f2bf(b.y); bb.z = f2bf(b.z); bb.w = f2bf(b.w);
      *reinterpret_cast<ushort4*>(&Bs[(i * 16 + srow) * LDP + (t & 15) * 4]) = bb;
    }
    // issue next K-tile's loads now; they land during the MFMA phase
    if (kt + BK < 256) {
#pragma unroll
      for (int i = 0; i < 8; i++) {
        rA[i] = *reinterpret_cast<const float4*>(
            &F[(size_t)(m0 + i * 16 + srow) * 256 + kt + BK + scol]);
        rB[i] = *reinterpret_cast<const float4*>(
            &C[(size_t)(n0 + i * 16 + srow) * 256 + kt + BK + scol]);
      }
    }
    __syncthreads();
#pragma unroll
    for (int kk = 0; kk < 2; ++kk) {
      bf16x8 af[4], bfr[4];
#pragma unroll
      for (int mi = 0; mi < 4; mi++)
        af[mi] = *reinterpret_cast<const bf16x8*>(
            &As[(wr * 64 + mi * 16 + rl) * LDP + kk * 32 + kh * 8]);
#pragma unroll
      for (int ni = 0; ni < 4; ni++)
        bfr[ni] = *reinterpret_cast<const bf16x8*>(
            &Bs[(wc * 64 + ni * 16 + rl) * LDP + kk * 32 + kh * 8]);
#pragma unroll
      for (int mi = 0; mi < 4; mi++)
#pragma unroll
        for (int ni = 0; ni < 4; ni++)
          acc[mi][ni] = __builtin_amdgcn_mfma_f32_16x16x32_bf16(
              af[mi], bfr[ni], acc[mi][ni], 0, 0, 0);
    }
    __syncthreads();
  }

  // Reduce per-thread square partials across the 16 threads sharing a row.
#pragma unroll
  for (int i = 0; i < 8; i++) {
    float v = rsqA[i];
    v += __shfl_xor(v, 1); v += __shfl_xor(v, 2);
    v += __shfl_xor(v, 4); v += __shfl_xor(v, 8);
    float u = rsqB[i];
    u += __shfl_xor(u, 1); u += __shfl_xor(u, 2);
    u += __shfl_xor(u, 4); u += __shfl_xor(u, 8);
    if ((t & 15) == 0) {
      fsq_s[i * 16 + srow] = v;
      csq_s[i * 16 + srow] = u;
    }
  }
  __syncthreads();

  // Epilogue: C/D layout col = lane&15, row = (lane>>4)*4 + reg  [m89/m91]
#pragma unroll
  for (int mi = 0; mi < 4; mi++) {
    const int rloc = wr * 64 + mi * 16 + kh * 4;
    float fr[4];
#pragma unroll
    for (int r = 0; r < 4; r++) fr[r] = fsq_s[rloc + r];
#pragma unroll
    for (int ni = 0; ni < 4; ni++) {
      const int cloc = wc * 64 + ni * 16 + rl;
      const float cs = csq_s[cloc];
#pragma unroll
      for (int r = 0; r < 4; r++)
        out[(size_t)(m0 + rloc + r) * N + n0 + cloc] = fr[r] + cs - 2.0f * acc[mi][ni][r];
    }
  }
}

extern "C" void kernel_launch(void* const* d_in, const int* in_sizes, int n_in,
                              void* d_out, int out_size, void* d_ws, size_t ws_size,
                              hipStream_t stream) {
  const float* F = (const float*)d_in[0];   // (16, 2048, 256) fp32
  const float* C = (const float*)d_in[1];   // (1, 512, 256) fp32
  float* out = (float*)d_out;               // (16, 2048, 512) fp32
  const int D = 256;
  const int M = in_sizes[0] / D;            // 32768
  const int N = in_sizes[1] / D;            // 512

  const int nwg = (M / BM) * (N / BN);      // 1024, divisible by 8
  hipLaunchKernelGGL(dist_fused, dim3(nwg), dim3(256), 0, stream, F, C, out, M, N);
}

// Round 3
// 32.736 us; speedup vs baseline: 1.3935x; 1.3935x over previous
//
#include <hip/hip_runtime.h>

typedef __attribute__((ext_vector_type(8))) short bf16x8;   // 8 bf16 (4 VGPRs)
typedef __attribute__((ext_vector_type(4))) float f32x4;

#define D_DIM 256   // feature dim (bf16 row = 512 B)
#define BM 128
#define BN 128
#define BK 128      // K-step in elements (256 B per row-half)

__device__ inline unsigned short f2bf(float f) {
  unsigned int u = __builtin_bit_cast(unsigned int, f);
  u += 0x7fffu + ((u >> 16) & 1u);     // round-to-nearest-even
  return (unsigned short)(u >> 16);
}

__device__ inline void gload16(const void* g, void* l) {
  __builtin_amdgcn_global_load_lds(
      (const __attribute__((address_space(1))) void*)g,
      (__attribute__((address_space(3))) void*)l, 16, 0, 0);
}

// One wave per row. Writes bf16 copy PRE-XOR-SWIZZLED (byte ^= (row&7)<<4
// within the 512B row) + exact fp32 sum-of-squares.
// Rows [0,M) come from F -> Abf/fsq; rows [M,M+K) from C -> Cbf/csq.
__global__ void prep_rows(const float* __restrict__ F, const float* __restrict__ C,
                          unsigned short* __restrict__ Abf, unsigned short* __restrict__ Cbf,
                          float* __restrict__ fsq, float* __restrict__ csq, int M) {
  const int w = threadIdx.x >> 6, lane = threadIdx.x & 63;
  int row = blockIdx.x * 4 + w;
  const float* src;
  unsigned short* dst;
  float* rsq;
  if (row < M) {
    src = F; dst = Abf; rsq = fsq;
  } else {
    row -= M;
    src = C; dst = Cbf; rsq = csq;
  }
  const float4 v = *reinterpret_cast<const float4*>(&src[(size_t)row * D_DIM + lane * 4]);
  ushort4 b;
  b.x = f2bf(v.x); b.y = f2bf(v.y); b.z = f2bf(v.z); b.w = f2bf(v.w);
  const int boff = (lane * 8) ^ ((row & 7) << 4);   // swizzled byte offset in 512B row
  *reinterpret_cast<ushort4*>((char*)dst + (size_t)row * 512 + boff) = b;
  float sq = v.x * v.x + v.y * v.y + v.z * v.z + v.w * v.w;
#pragma unroll
  for (int o = 32; o; o >>= 1) sq += __shfl_xor(sq, o);
  if (lane == 0) rsq[row] = sq;
}

// out[m][n] = fsq[m] + csq[n] - 2 * sum_d A[m][d]*B[n][d]
// A: M x 256 bf16 (swizzled rows), B: N x 256 bf16 (swizzled rows).
// 128x128 tile, BK=128 (2 K-iters), 4 waves (2x2, 64x64 each), single 64KB
// LDS buffer, all staging via global_load_lds (linear dest; source is
// pre-swizzled so ds_read applies the XOR).
__global__ __launch_bounds__(256, 2) void dist_gemm(
    const unsigned short* __restrict__ A, const unsigned short* __restrict__ B,
    const float* __restrict__ fsq, const float* __restrict__ csq,
    float* __restrict__ out, int M, int N) {
  __shared__ unsigned short As[BM * BK];   // 32 KB, rows of 256 B
  __shared__ unsigned short Bs[BN * BK];   // 32 KB

  const int t = threadIdx.x;
  const int w = t >> 6, lane = t & 63;
  const int wr = w >> 1, wc = w & 1;          // wave -> 64x64 quadrant
  const int rl = lane & 15, kh = lane >> 4;   // fragment lane decomposition

  // Bijective XCD swizzle (1024 blocks, %8==0); n-tile fastest so the 4
  // blocks sharing an A m-panel land consecutively on the same XCD.
  const int nwg = gridDim.x;
  const int cpx = nwg >> 3;
  const int work = (blockIdx.x & 7) * cpx + (blockIdx.x >> 3);
  const int ntiles = N / BN;                  // 4
  const int n0 = (work % ntiles) * BN;
  const int m0 = (work / ntiles) * BM;

  // Prefetch the norm terms into registers (L2-hot, hides under staging).
  float fr[4][4];
#pragma unroll
  for (int mi = 0; mi < 4; mi++)
#pragma unroll
    for (int r = 0; r < 4; r++)
      fr[mi][r] = fsq[m0 + wr * 64 + mi * 16 + kh * 4 + r];
  float cs[4];
#pragma unroll
  for (int ni = 0; ni < 4; ni++)
    cs[ni] = csq[n0 + wc * 64 + ni * 16 + rl];

  f32x4 acc[4][4];
#pragma unroll
  for (int i = 0; i < 4; i++)
#pragma unroll
    for (int j = 0; j < 4; j++) acc[i][j] = (f32x4){0.f, 0.f, 0.f, 0.f};

  const int srow = t >> 4;          // 0..15 row within a 16-row staging chunk
  const int scb = (t & 15) * 16;    // byte col within 256B half-row

  for (int kt = 0; kt < 2; ++kt) {
    const size_t ktoff = (size_t)kt * 256;   // byte offset of K-half in 512B row
#pragma unroll
    for (int j = 0; j < 8; ++j) {
      const int row = j * 16 + srow;
      gload16((const char*)A + (size_t)(m0 + row) * 512 + ktoff + scb,
              (char*)As + j * 4096 + w * 1024);
      gload16((const char*)B + (size_t)(n0 + row) * 512 + ktoff + scb,
              (char*)Bs + j * 4096 + w * 1024);
    }
    __syncthreads();   // compiler drains vmcnt before barrier
#pragma unroll
    for (int kk = 0; kk < 4; ++kk) {
      const int doff = kk * 64 + kh * 16;          // logical byte col in half-row
      const int soff = doff ^ ((rl & 7) << 4);     // swizzled
      bf16x8 af[4], bfr[4];
#pragma unroll
      for (int mi = 0; mi < 4; mi++)
        af[mi] = *reinterpret_cast<const bf16x8*>(
            (const char*)As + (wr * 64 + mi * 16 + rl) * 256 + soff);
#pragma unroll
      for (int ni = 0; ni < 4; ni++)
        bfr[ni] = *reinterpret_cast<const bf16x8*>(
            (const char*)Bs + (wc * 64 + ni * 16 + rl) * 256 + soff);
#pragma unroll
      for (int mi = 0; mi < 4; mi++)
#pragma unroll
        for (int ni = 0; ni < 4; ni++)
          acc[mi][ni] = __builtin_amdgcn_mfma_f32_16x16x32_bf16(
              af[mi], bfr[ni], acc[mi][ni], 0, 0, 0);
    }
    __syncthreads();
  }

  // Epilogue: C/D layout col = lane&15, row = (lane>>4)*4 + reg  [m89/m91]
#pragma unroll
  for (int mi = 0; mi < 4; mi++) {
    const int rloc = wr * 64 + mi * 16 + kh * 4;
#pragma unroll
    for (int ni = 0; ni < 4; ni++) {
      const int cloc = wc * 64 + ni * 16 + rl;
#pragma unroll
      for (int r = 0; r < 4; r++)
        out[(size_t)(m0 + rloc + r) * N + n0 + cloc] =
            fr[mi][r] + cs[ni] - 2.0f * acc[mi][ni][r];
    }
  }
}

extern "C" void kernel_launch(void* const* d_in, const int* in_sizes, int n_in,
                              void* d_out, int out_size, void* d_ws, size_t ws_size,
                              hipStream_t stream) {
  const float* F = (const float*)d_in[0];   // (16, 2048, 256) fp32
  const float* C = (const float*)d_in[1];   // (1, 512, 256) fp32
  float* out = (float*)d_out;               // (16, 2048, 512) fp32
  const int M = in_sizes[0] / D_DIM;        // 32768
  const int N = in_sizes[1] / D_DIM;        // 512

  unsigned short* Abf = (unsigned short*)d_ws;            // M*256 bf16 (swizzled)
  unsigned short* Cbf = Abf + (size_t)M * D_DIM;          // N*256 bf16 (swizzled)
  float* fsq = (float*)(Cbf + (size_t)N * D_DIM);         // M fp32
  float* csq = fsq + M;                                   // N fp32

  hipLaunchKernelGGL(prep_rows, dim3((M + N) / 4), dim3(256), 0, stream,
                     F, C, Abf, Cbf, fsq, csq, M);
  const int nwg = (M / BM) * (N / BN);      // 1024, divisible by 8
  hipLaunchKernelGGL(dist_gemm, dim3(nwg), dim3(256), 0, stream,
                     Abf, Cbf, fsq, csq, out, M, N);
}